// Round 15
// baseline (183.443 us; speedup 1.0000x reference)
//
#include <hip/hip_runtime.h>

typedef __attribute__((ext_vector_type(8))) short bf16x8;
typedef __attribute__((ext_vector_type(4))) float f32x4;
typedef __attribute__((ext_vector_type(16))) float f32x16;

__device__ __forceinline__ ushort f2bf(float f) {
  union { float f; unsigned u; } v; v.f = f;
  unsigned r = v.u + 0x7fffu + ((v.u >> 16) & 1u);
  return (ushort)(r >> 16);
}

__device__ __forceinline__ float bf2f(ushort u) {
  union { float f; unsigned u; } v; v.u = (unsigned)u << 16;
  return v.f;
}

__device__ __forceinline__ unsigned cvt_pk_bf16(float lo, float hi) {
  unsigned r;
  asm("v_cvt_pk_bf16_f32 %0, %1, %2" : "=v"(r) : "v"(lo), "v"(hi));
  return r;
}

__device__ __forceinline__ void permlane32_swap(unsigned& x, unsigned& y) {
  asm("v_permlane32_swap_b32 %0, %1" : "+v"(x), "+v"(y));
}

__device__ __forceinline__ void gload_lds16(const void* g, void* l) {
  __builtin_amdgcn_global_load_lds(
      (const __attribute__((address_space(1))) void*)g,
      (__attribute__((address_space(3))) void*)l, 16, 0, 0);
}

// ---------------- fused prep (r14) ----------------

__global__ __launch_bounds__(256) void prep(const float* __restrict__ x,
                                            const float* __restrict__ w_qkv,
                                            const float* __restrict__ w_out,
                                            ushort* __restrict__ xb,
                                            ushort* __restrict__ wqkvT,
                                            ushort* __restrict__ woutT) {
  const int bid = blockIdx.x, tid = threadIdx.x;
  if (bid < 2048) {
    int i = (bid * 256 + tid) * 4;
    const int stride = 2048 * 256 * 4;
    for (; i < 8192 * 1024; i += stride) {
      float4 v = *reinterpret_cast<const float4*>(x + i);
      ushort4 o;
      o.x = f2bf(v.x); o.y = f2bf(v.y); o.z = f2bf(v.z); o.w = f2bf(v.w);
      *reinterpret_cast<ushort4*>(xb + i) = o;
    }
    return;
  }
  __shared__ float tile[32][33];
  const int tx = tid & 31, ty = tid >> 5;  // 32 x 8
  const float* src; ushort* dst; int R, C, c0, r0;
  if (bid < 5120) {
    const int tb = bid - 2048;             // [0,3072): 96 x 32
    src = w_qkv; dst = wqkvT; R = 1024; C = 3072;
    c0 = (tb % 96) * 32; r0 = (tb / 96) * 32;
  } else {
    const int tb = bid - 5120;             // [0,1024): 32 x 32
    src = w_out; dst = woutT; R = 1024; C = 1024;
    c0 = (tb % 32) * 32; r0 = (tb / 32) * 32;
  }
  #pragma unroll
  for (int i = 0; i < 32; i += 8)
    tile[ty + i][tx] = src[(size_t)(r0 + ty + i) * C + c0 + tx];
  __syncthreads();
  #pragma unroll
  for (int i = 0; i < 32; i += 8)
    dst[(size_t)(c0 + ty + i) * R + r0 + tx] = f2bf(tile[tx][ty + i]);
}

// ================= gemm_qk: 256x256 8-phase (r10-proven) =================

#define QK_STAGE(Sp, Gp, base, kt)                                             \
  {                                                                            \
    _Pragma("unroll")                                                          \
    for (int c_ = 0; c_ < 4; ++c_) {                                           \
      const int qq_ = c_ * 512 + tid;                                          \
      const int row_ = qq_ >> 3;                                               \
      const int so_ = ((qq_ & 7) ^ (row_ & 7)) * 8;                            \
      gload_lds16(Gp + (size_t)((base) + row_) * 1024 + (kt) + so_,            \
                  (char*)Sp + qq_ * 16);                                       \
    }                                                                          \
  }

#define QK_LDA(buf, mh)                                                        \
  {                                                                            \
    _Pragma("unroll")                                                          \
    for (int mi = 0; mi < 4; ++mi) {                                           \
      const int row_ = wm * 128 + (mh) * 64 + mi * 16 + lr;                    \
      const char* p_ = (const char*)&sA[buf][0] + row_ * 128;                  \
      const int sw_ = (row_ & 7) << 4;                                         \
      af[mi][0] = *(const bf16x8*)(p_ + ((lg * 16) ^ sw_));                    \
      af[mi][1] = *(const bf16x8*)(p_ + ((64 + lg * 16) ^ sw_));               \
    }                                                                          \
  }

#define QK_LDB(buf, nh)                                                        \
  {                                                                            \
    _Pragma("unroll")                                                          \
    for (int ni = 0; ni < 2; ++ni) {                                           \
      const int row_ = wn * 64 + (nh) * 32 + ni * 16 + lr;                     \
      const char* p_ = (const char*)&sB[buf][0] + row_ * 128;                  \
      const int sw_ = (row_ & 7) << 4;                                         \
      bf[ni][0] = *(const bf16x8*)(p_ + ((lg * 16) ^ sw_));                    \
      bf[ni][1] = *(const bf16x8*)(p_ + ((64 + lg * 16) ^ sw_));               \
    }                                                                          \
  }

#define QK_MMQ(mh, nh)                                                         \
  {                                                                            \
    _Pragma("unroll")                                                          \
    for (int kk = 0; kk < 2; ++kk)                                             \
      _Pragma("unroll")                                                        \
      for (int mi = 0; mi < 4; ++mi)                                           \
        _Pragma("unroll")                                                      \
        for (int ni = 0; ni < 2; ++ni)                                         \
          acc[mh][mi][nh][ni] = __builtin_amdgcn_mfma_f32_16x16x32_bf16(       \
              af[mi][kk], bf[ni][kk], acc[mh][mi][nh][ni], 0, 0, 0);           \
  }

#define QK_SYNC_MMQ(mh, nh)                                                    \
  __builtin_amdgcn_s_barrier();                                                \
  asm volatile("s_waitcnt lgkmcnt(0)" ::: "memory");                           \
  __builtin_amdgcn_sched_barrier(0);                                           \
  __builtin_amdgcn_s_setprio(1);                                               \
  QK_MMQ(mh, nh);                                                              \
  __builtin_amdgcn_s_setprio(0);                                               \
  __builtin_amdgcn_s_barrier();

__global__ __launch_bounds__(512, 1) void gemm_qk(const ushort* __restrict__ A,
                                                  const ushort* __restrict__ Bt,
                                                  const float* __restrict__ bias,
                                                  ushort* __restrict__ q,
                                                  ushort* __restrict__ k) {
  __shared__ __align__(16) ushort sA[2][256 * 64];
  __shared__ __align__(16) ushort sB[2][256 * 64];
  const int tid = threadIdx.x, lane = tid & 63, w = tid >> 6;
  const int wm = w >> 2, wn = w & 3;
  const int lr = lane & 15, lg = lane >> 4;

  const int id = blockIdx.x;                 // 256 blocks, bijective
  const int xcd = id & 7, j = id >> 3;       // j in [0,32)
  const int by = xcd * 4 + (j & 3);          // [0,32)
  const int bx = j >> 2;                     // [0,8)
  const int bm = by * 256, bn = bx * 256;

  f32x4 acc[2][4][2][2] = {};
  bf16x8 af[4][2], bf[2][2];

  QK_STAGE(&sA[0][0], A, bm, 0);
  QK_STAGE(&sB[0][0], Bt, bn, 0);
  asm volatile("s_waitcnt vmcnt(0)" ::: "memory");
  __builtin_amdgcn_s_barrier();

  for (int T = 0; T < 16; ++T) {
    const int cur = T & 1;
    const bool pf = (T + 1 < 16);
    QK_LDA(cur, 0); QK_LDB(cur, 0);
    if (pf) QK_STAGE(&sA[cur ^ 1][0], A, bm, (T + 1) * 64);
    QK_SYNC_MMQ(0, 0);
    QK_LDB(cur, 1);
    if (pf) QK_STAGE(&sB[cur ^ 1][0], Bt, bn, (T + 1) * 64);
    QK_SYNC_MMQ(0, 1);
    QK_LDA(cur, 1);
    QK_SYNC_MMQ(1, 1);
    QK_LDB(cur, 0);
    asm volatile("s_waitcnt vmcnt(0)" ::: "memory");
    QK_SYNC_MMQ(1, 0);
  }

  ushort* const dst = (bn < 1024) ? q : k;   // block-uniform
  const int cb = bn & 1023;
  #pragma unroll
  for (int mh = 0; mh < 2; ++mh)
    #pragma unroll
    for (int mi = 0; mi < 4; ++mi)
      #pragma unroll
      for (int nh = 0; nh < 2; ++nh)
        #pragma unroll
        for (int ni = 0; ni < 2; ++ni) {
          const int cq = cb + wn * 64 + nh * 32 + ni * 16 + lr;
          const int h = cq >> 6, d = cq & 63;
          const float bb = bias[bn + wn * 64 + nh * 32 + ni * 16 + lr];
          #pragma unroll
          for (int r = 0; r < 4; ++r) {
            const int row = bm + wm * 128 + mh * 64 + mi * 16 + lg * 4 + r;
            const int b_ = row >> 11, n = row & 2047;
            const int bh = b_ * 16 + h;
            dst[((size_t)bh * 2048 + n) * 64 + d] = f2bf(acc[mh][mi][nh][ni][r] + bb);
          }
        }
}

// ---------------- GEMM core 128x128 (vT/out): counted-vmcnt 2-phase (r10) ----

#define GEMM_STAGE(buf, Ap, Bp, kt)                                            \
  {                                                                            \
    _Pragma("unroll")                                                          \
    for (int c_ = 0; c_ < 4; ++c_) {                                           \
      const int qq_ = c_ * 256 + tid;                                          \
      const int row_ = qq_ >> 3;                                               \
      const int so_ = ((qq_ & 7) ^ (row_ & 7)) * 8;                            \
      gload_lds16(Ap + (size_t)(bm + row_) * 1024 + (kt) + so_,                \
                  (char*)sA + (buf) * 16384 + qq_ * 16);                       \
      gload_lds16(Bp + (size_t)(bn + row_) * 1024 + (kt) + so_,                \
                  (char*)sB + (buf) * 16384 + qq_ * 16);                       \
    }                                                                          \
  }

#define GEMM_COMPUTE(buf)                                                      \
  {                                                                            \
    const char* bA_ = (const char*)sA + (buf) * 16384;                         \
    const char* bB_ = (const char*)sB + (buf) * 16384;                         \
    bf16x8 af[4][2], bfr[4][2];                                                \
    _Pragma("unroll")                                                          \
    for (int mi = 0; mi < 4; ++mi) {                                           \
      const int row_ = wr * 64 + mi * 16 + lr;                                 \
      const char* p_ = bA_ + row_ * 128;                                       \
      const int sw_ = (row_ & 7) << 4;                                         \
      af[mi][0] = *(const bf16x8*)(p_ + ((lg * 16) ^ sw_));                    \
      af[mi][1] = *(const bf16x8*)(p_ + ((64 + lg * 16) ^ sw_));               \
    }                                                                          \
    _Pragma("unroll")                                                          \
    for (int ni = 0; ni < 4; ++ni) {                                           \
      const int row_ = wc * 64 + ni * 16 + lr;                                 \
      const char* p_ = bB_ + row_ * 128;                                       \
      const int sw_ = (row_ & 7) << 4;                                         \
      bfr[ni][0] = *(const bf16x8*)(p_ + ((lg * 16) ^ sw_));                   \
      bfr[ni][1] = *(const bf16x8*)(p_ + ((64 + lg * 16) ^ sw_));              \
    }                                                                          \
    _Pragma("unroll")                                                          \
    for (int kk = 0; kk < 2; ++kk)                                             \
      _Pragma("unroll")                                                        \
      for (int mi = 0; mi < 4; ++mi)                                           \
        _Pragma("unroll")                                                      \
        for (int ni = 0; ni < 4; ++ni)                                         \
          acc[mi][ni] = __builtin_amdgcn_mfma_f32_16x16x32_bf16(               \
              af[mi][kk], bfr[ni][kk], acc[mi][ni], 0, 0, 0);                  \
  }

#define GEMM_PIPELINE(Ap, Bp)                                                  \
  GEMM_STAGE(0, Ap, Bp, 0);                                                    \
  for (int T = 0; T < 16; ++T) {                                               \
    if (T + 1 < 16) {                                                          \
      GEMM_STAGE((T + 1) & 1, Ap, Bp, (T + 1) * 64);                           \
      asm volatile("s_waitcnt vmcnt(8)" ::: "memory");                         \
    } else {                                                                   \
      asm volatile("s_waitcnt vmcnt(0)" ::: "memory");                         \
    }                                                                          \
    __builtin_amdgcn_s_barrier();                                              \
    __builtin_amdgcn_sched_barrier(0);                                         \
    GEMM_COMPUTE(T & 1);                                                       \
    __builtin_amdgcn_s_barrier();                                              \
  }

#define GEMM_PROLOG                                                            \
  __shared__ __align__(16) ushort sA[2][128 * 64];                             \
  __shared__ __align__(16) ushort sB[2][128 * 64];                             \
  const int tid = threadIdx.x;                                                 \
  const int lane = tid & 63;                                                   \
  const int w = tid >> 6;                                                      \
  const int wr = w >> 1, wc = w & 1;                                           \
  const int lr = lane & 15, lg = lane >> 4;                                    \
  f32x4 acc[4][4] = {};

// ---------------- GEMM1b: vT (r10) ----------------

__global__ __launch_bounds__(256) void gemm_vT(const ushort* __restrict__ A,
                                               const ushort* __restrict__ Bt,
                                               const float* __restrict__ bias,
                                               ushort* __restrict__ vT) {
  GEMM_PROLOG;
  const int id = blockIdx.x;                // 512 blocks
  const int xcd = id & 7, j = id >> 3;      // j in [0,64)
  const int bnb = xcd * 8 + (j & 7);        // token-block [0,64)
  const int bmb = j >> 3;                   // v-col block [0,8)
  const int bm = bmb * 128;
  const int bn = bnb * 128;

  GEMM_PIPELINE(A, Bt);

  const int b_ = bn >> 11, n0 = bn & 2047;
  #pragma unroll
  for (int mi = 0; mi < 4; ++mi)
    #pragma unroll
    for (int ni = 0; ni < 4; ++ni) {
      const int ncol = wc * 64 + ni * 16 + lr;
      #pragma unroll
      for (int r = 0; r < 4; ++r) {
        const int m = wr * 64 + mi * 16 + lg * 4 + r;
        const int vc = bm + m;
        const int h = vc >> 6, d = vc & 63;
        const int bh = b_ * 16 + h;
        const float bb = bias[vc];
        vT[((size_t)bh * 64 + d) * 2048 + n0 + ncol] = f2bf(acc[mi][ni][r] + bb);
      }
    }
}

// ---------------- GEMM2: out (r10) ----------------

__global__ __launch_bounds__(256) void gemm_out(const ushort* __restrict__ A,
                                                const ushort* __restrict__ Bt,
                                                const float* __restrict__ bias,
                                                float* __restrict__ out) {
  GEMM_PROLOG;
  const int id = blockIdx.x;                // 512 blocks
  const int xcd = id & 7, j = id >> 3;      // j in [0,64)
  const int by = xcd * 8 + (j & 7);         // A-row block [0,64)
  const int bx = j >> 3;                    // col block [0,8)
  const int bm = by * 128;
  const int bn = bx * 128;

  GEMM_PIPELINE(A, Bt);

  #pragma unroll
  for (int mi = 0; mi < 4; ++mi)
    #pragma unroll
    for (int ni = 0; ni < 4; ++ni) {
      const int col = bn + wc * 64 + ni * 16 + lr;
      const float bb = bias[col];
      #pragma unroll
      for (int r = 0; r < 4; ++r) {
        const int row = bm + wr * 64 + mi * 16 + lg * 4 + r;
        out[(size_t)row * 1024 + col] = acc[mi][ni][r] + bb;
      }
    }
}

// ---------------- flash attention v8: r10 + per-kvt softmax||PV interleave ----

__global__ __launch_bounds__(512, 2) void attn_fwd(const ushort* __restrict__ q,
                                                   const ushort* __restrict__ k,
                                                   const ushort* __restrict__ vT,
                                                   ushort* __restrict__ o) {
  __shared__ __align__(16) ushort sK[2][64 * 64];
  __shared__ __align__(16) ushort sV[2][64 * 64];

  const int tid = threadIdx.x, lane = tid & 63, w = tid >> 6;
  const int id = blockIdx.x;
  const int xcd = id & 7, j = id >> 3;
  const int bh = xcd * 8 + (j & 7);
  const int qx = j >> 3;
  const int qrow0 = qx * 256 + w * 32;

  const ushort* Qb = q + (size_t)bh * 2048 * 64;
  const ushort* Kb = k + (size_t)bh * 2048 * 64;
  const ushort* Vb = vT + (size_t)bh * 64 * 2048;
  const int lq = lane & 31, hi = lane >> 5;

  const int srow = lane >> 3;
  const int ssw = ((lane & 7) ^ srow) * 8;
  const int krow = w * 8 + srow;

  gload_lds16(Kb + (size_t)krow * 64 + ssw, &sK[0][w * 512]);
  gload_lds16(Vb + (size_t)krow * 2048 + 0 + ssw, &sV[0][w * 512]);

  const float qs = 0.125f * 1.44269504f;  // 1/sqrt(64) * log2(e)
  bf16x8 qf[4];
  #pragma unroll
  for (int dk = 0; dk < 4; ++dk) {
    bf16x8 t = *(const bf16x8*)(Qb + (size_t)(qrow0 + lq) * 64 + dk * 16 + hi * 8);
    #pragma unroll
    for (int jj = 0; jj < 8; ++jj)
      t[jj] = (short)f2bf(bf2f((ushort)t[jj]) * qs);
    qf[dk] = t;
  }

  float m_run = -1e30f, l_run = 0.f;
  f32x16 oacc[2] = {};

  for (int t = 0; t < 32; ++t) {
    const int cur = t & 1;
    if (t + 1 < 32) {
      const int kv2 = (t + 1) << 6;
      gload_lds16(Kb + (size_t)(kv2 + krow) * 64 + ssw, &sK[cur ^ 1][w * 512]);
      gload_lds16(Vb + (size_t)krow * 2048 + kv2 + ssw, &sV[cur ^ 1][w * 512]);
      asm volatile("s_waitcnt vmcnt(2)" ::: "memory");
    } else {
      asm volatile("s_waitcnt vmcnt(0)" ::: "memory");
    }
    __builtin_amdgcn_s_barrier();
    __builtin_amdgcn_sched_barrier(0);

    const char* kb_ = (const char*)&sK[cur][0];
    const char* vb_ = (const char*)&sV[cur][0];

    f32x16 S[2] = {};
    __builtin_amdgcn_s_setprio(1);
    #pragma unroll
    for (int kvt = 0; kvt < 2; ++kvt) {
      const int row = kvt * 32 + lq;
      const int rsw = (row & 7) << 4;
      #pragma unroll
      for (int dk = 0; dk < 4; ++dk) {
        bf16x8 kf = *(const bf16x8*)(kb_ + row * 128 + ((dk * 32 + hi * 16) ^ rsw));
        S[kvt] = __builtin_amdgcn_mfma_f32_32x32x16_bf16(kf, qf[dk], S[kvt], 0, 0, 0);
      }
    }
    __builtin_amdgcn_s_setprio(0);

    // tree row max (nested fmax -> v_max3 fusion opportunities)
    float tm[8];
    #pragma unroll
    for (int r = 0; r < 8; ++r)
      tm[r] = fmaxf(fmaxf(S[0][r], S[0][r + 8]), fmaxf(S[1][r], S[1][r + 8]));
    #pragma unroll
    for (int sgap = 4; sgap > 0; sgap >>= 1)
      #pragma unroll
      for (int r = 0; r < sgap; ++r) tm[r] = fmaxf(tm[r], tm[r + sgap]);
    const float rm = fmaxf(tm[0], __shfl_xor(tm[0], 32, 64));

    if (!__all(rm <= m_run + 8.f)) {
      const float mnew = fmaxf(m_run, rm);
      const float corr = __builtin_amdgcn_exp2f(m_run - mnew);
      m_run = mnew;
      l_run *= corr;
      float cq[16];
      #pragma unroll
      for (int r = 0; r < 16; ++r)
        cq[r] = __shfl(corr, (r & 3) + 8 * (r >> 2) + 4 * hi, 64);
      #pragma unroll
      for (int dt = 0; dt < 2; ++dt)
        #pragma unroll
        for (int r = 0; r < 16; ++r) oacc[dt][r] *= cq[r];
    }

    // per-kvt: exp + pack + tree-sum, then PV MFMAs immediately (pipe overlap)
    float psum = 0.f;
    #pragma unroll
    for (int kvt = 0; kvt < 2; ++kvt) {
      float e[16];
      #pragma unroll
      for (int r = 0; r < 16; ++r)
        e[r] = __builtin_amdgcn_exp2f(S[kvt][r] - m_run);
      unsigned pk_[8];
      #pragma unroll
      for (int g = 0; g < 4; ++g) {
        pk_[g * 2 + 0] = cvt_pk_bf16(e[4 * g + 0], e[4 * g + 1]);
        pk_[g * 2 + 1] = cvt_pk_bf16(e[4 * g + 2], e[4 * g + 3]);
      }
      float ts[8];
      #pragma unroll
      for (int r = 0; r < 8; ++r) ts[r] = e[r] + e[r + 8];
      #pragma unroll
      for (int sgap = 4; sgap > 0; sgap >>= 1)
        #pragma unroll
        for (int r = 0; r < sgap; ++r) ts[r] += ts[r + sgap];
      psum += ts[0];

      __builtin_amdgcn_s_setprio(1);
      #pragma unroll
      for (int cc = 0; cc < 2; ++cc) {
        unsigned x0 = pk_[4 * cc + 0], x1 = pk_[4 * cc + 1];
        unsigned y0 = pk_[4 * cc + 2], y1 = pk_[4 * cc + 3];
        permlane32_swap(x0, y0);
        permlane32_swap(x1, y1);
        union { unsigned u[4]; bf16x8 v; } Am;
        Am.u[0] = x0; Am.u[1] = x1; Am.u[2] = y0; Am.u[3] = y1;
        const int cg = kvt * 2 + cc;
        #pragma unroll
        for (int dt = 0; dt < 2; ++dt) {
          const int row = dt * 32 + lq;
          bf16x8 vf = *(const bf16x8*)(vb_ + row * 128 + ((cg * 32 + hi * 16) ^ ((row & 7) << 4)));
          oacc[dt] = __builtin_amdgcn_mfma_f32_32x32x16_bf16(Am.v, vf, oacc[dt], 0, 0, 0);
        }
      }
      __builtin_amdgcn_s_setprio(0);
    }
    psum += __shfl_xor(psum, 32, 64);
    l_run += psum;

    __builtin_amdgcn_s_barrier();
  }

  const int b_ = bh >> 4, h = bh & 15;
  float lf[16];
  #pragma unroll
  for (int r = 0; r < 16; ++r)
    lf[r] = __builtin_amdgcn_rcpf(__shfl(l_run, (r & 3) + 8 * (r >> 2) + 4 * hi, 64));
  #pragma unroll
  for (int dt = 0; dt < 2; ++dt)
    #pragma unroll
    for (int r = 0; r < 16; ++r) {
      const int n = qrow0 + (r & 3) + 8 * (r >> 2) + 4 * hi;
      o[(((size_t)b_ * 2048 + n) * 16 + h) * 64 + dt * 32 + lq] = f2bf(oacc[dt][r] * lf[r]);
    }
}

// ---------------- launch ----------------

extern "C" void kernel_launch(void* const* d_in, const int* in_sizes, int n_in,
                              void* d_out, int out_size, void* d_ws, size_t ws_size,
                              hipStream_t stream) {
  const float* x = (const float*)d_in[0];
  const float* w_qkv = (const float*)d_in[1];
  const float* b_qkv = (const float*)d_in[2];
  const float* w_out = (const float*)d_in[3];
  const float* b_out = (const float*)d_in[4];
  float* out = (float*)d_out;
  char* ws = (char*)d_ws;

  ushort* xb    = (ushort*)(ws);                 // 16 MiB
  ushort* wqkvT = (ushort*)(ws + 16777216);      // 6 MiB
  ushort* woutT = (ushort*)(ws + 23068672);      // 2 MiB
  ushort* qb    = (ushort*)(ws + 25165824);      // 16 MiB
  ushort* kb    = (ushort*)(ws + 41943040);      // 16 MiB
  ushort* vTb   = (ushort*)(ws + 58720256);      // 16 MiB
  ushort* attnb = (ushort*)(ws + 75497472);      // 16 MiB

  prep<<<6144, 256, 0, stream>>>(x, w_qkv, w_out, xb, wqkvT, woutT);
  gemm_qk<<<256, 512, 0, stream>>>(xb, wqkvT, b_qkv, qb, kb);
  gemm_vT<<<512, 256, 0, stream>>>(wqkvT + 2048 * 1024, xb, b_qkv + 2048, vTb);
  attn_fwd<<<512, 512, 0, stream>>>(qb, kb, vTb, attnb);
  gemm_out<<<512, 256, 0, stream>>>(attnb, woutT, b_out, out);
}

// Round 16
// 181.568 us; speedup vs baseline: 1.0103x; 1.0103x over previous
//
#include <hip/hip_runtime.h>

typedef __attribute__((ext_vector_type(8))) short bf16x8;
typedef __attribute__((ext_vector_type(4))) float f32x4;
typedef __attribute__((ext_vector_type(16))) float f32x16;

__device__ __forceinline__ ushort f2bf(float f) {
  union { float f; unsigned u; } v; v.f = f;
  unsigned r = v.u + 0x7fffu + ((v.u >> 16) & 1u);
  return (ushort)(r >> 16);
}

__device__ __forceinline__ float bf2f(ushort u) {
  union { float f; unsigned u; } v; v.u = (unsigned)u << 16;
  return v.f;
}

__device__ __forceinline__ unsigned cvt_pk_bf16(float lo, float hi) {
  unsigned r;
  asm("v_cvt_pk_bf16_f32 %0, %1, %2" : "=v"(r) : "v"(lo), "v"(hi));
  return r;
}

__device__ __forceinline__ void permlane32_swap(unsigned& x, unsigned& y) {
  asm("v_permlane32_swap_b32 %0, %1" : "+v"(x), "+v"(y));
}

__device__ __forceinline__ void gload_lds16(const void* g, void* l) {
  __builtin_amdgcn_global_load_lds(
      (const __attribute__((address_space(1))) void*)g,
      (__attribute__((address_space(3))) void*)l, 16, 0, 0);
}

// ---------------- fused prep: cvt(x) + transpose(w_qkv) + transpose(w_out) ----

__global__ __launch_bounds__(256) void prep(const float* __restrict__ x,
                                            const float* __restrict__ w_qkv,
                                            const float* __restrict__ w_out,
                                            ushort* __restrict__ xb,
                                            ushort* __restrict__ wqkvT,
                                            ushort* __restrict__ woutT) {
  const int bid = blockIdx.x, tid = threadIdx.x;
  if (bid < 2048) {
    int i = (bid * 256 + tid) * 4;
    const int stride = 2048 * 256 * 4;
    for (; i < 8192 * 1024; i += stride) {
      float4 v = *reinterpret_cast<const float4*>(x + i);
      ushort4 o;
      o.x = f2bf(v.x); o.y = f2bf(v.y); o.z = f2bf(v.z); o.w = f2bf(v.w);
      *reinterpret_cast<ushort4*>(xb + i) = o;
    }
    return;
  }
  __shared__ float tile[32][33];
  const int tx = tid & 31, ty = tid >> 5;  // 32 x 8
  const float* src; ushort* dst; int R, C, c0, r0;
  if (bid < 5120) {
    const int tb = bid - 2048;             // [0,3072): 96 x 32
    src = w_qkv; dst = wqkvT; R = 1024; C = 3072;
    c0 = (tb % 96) * 32; r0 = (tb / 96) * 32;
  } else {
    const int tb = bid - 5120;             // [0,1024): 32 x 32
    src = w_out; dst = woutT; R = 1024; C = 1024;
    c0 = (tb % 32) * 32; r0 = (tb / 32) * 32;
  }
  #pragma unroll
  for (int i = 0; i < 32; i += 8)
    tile[ty + i][tx] = src[(size_t)(r0 + ty + i) * C + c0 + tx];
  __syncthreads();
  #pragma unroll
  for (int i = 0; i < 32; i += 8)
    dst[(size_t)(c0 + ty + i) * R + r0 + tx] = f2bf(tile[tx][ty + i]);
}

// ================= gemm_qk: 256x256 8-phase (r10-proven) =================

#define QK_STAGE(Sp, Gp, base, kt)                                             \
  {                                                                            \
    _Pragma("unroll")                                                          \
    for (int c_ = 0; c_ < 4; ++c_) {                                           \
      const int qq_ = c_ * 512 + tid;                                          \
      const int row_ = qq_ >> 3;                                               \
      const int so_ = ((qq_ & 7) ^ (row_ & 7)) * 8;                            \
      gload_lds16(Gp + (size_t)((base) + row_) * 1024 + (kt) + so_,            \
                  (char*)Sp + qq_ * 16);                                       \
    }                                                                          \
  }

#define QK_LDA(buf, mh)                                                        \
  {                                                                            \
    _Pragma("unroll")                                                          \
    for (int mi = 0; mi < 4; ++mi) {                                           \
      const int row_ = wm * 128 + (mh) * 64 + mi * 16 + lr;                    \
      const char* p_ = (const char*)&sA[buf][0] + row_ * 128;                  \
      const int sw_ = (row_ & 7) << 4;                                         \
      af[mi][0] = *(const bf16x8*)(p_ + ((lg * 16) ^ sw_));                    \
      af[mi][1] = *(const bf16x8*)(p_ + ((64 + lg * 16) ^ sw_));               \
    }                                                                          \
  }

#define QK_LDB(buf, nh)                                                        \
  {                                                                            \
    _Pragma("unroll")                                                          \
    for (int ni = 0; ni < 2; ++ni) {                                           \
      const int row_ = wn * 64 + (nh) * 32 + ni * 16 + lr;                     \
      const char* p_ = (const char*)&sB[buf][0] + row_ * 128;                  \
      const int sw_ = (row_ & 7) << 4;                                         \
      bf[ni][0] = *(const bf16x8*)(p_ + ((lg * 16) ^ sw_));                    \
      bf[ni][1] = *(const bf16x8*)(p_ + ((64 + lg * 16) ^ sw_));               \
    }                                                                          \
  }

#define QK_MMQ(mh, nh)                                                         \
  {                                                                            \
    _Pragma("unroll")                                                          \
    for (int kk = 0; kk < 2; ++kk)                                             \
      _Pragma("unroll")                                                        \
      for (int mi = 0; mi < 4; ++mi)                                           \
        _Pragma("unroll")                                                      \
        for (int ni = 0; ni < 2; ++ni)                                         \
          acc[mh][mi][nh][ni] = __builtin_amdgcn_mfma_f32_16x16x32_bf16(       \
              af[mi][kk], bf[ni][kk], acc[mh][mi][nh][ni], 0, 0, 0);           \
  }

#define QK_SYNC_MMQ(mh, nh)                                                    \
  __builtin_amdgcn_s_barrier();                                                \
  asm volatile("s_waitcnt lgkmcnt(0)" ::: "memory");                           \
  __builtin_amdgcn_sched_barrier(0);                                           \
  __builtin_amdgcn_s_setprio(1);                                               \
  QK_MMQ(mh, nh);                                                              \
  __builtin_amdgcn_s_setprio(0);                                               \
  __builtin_amdgcn_s_barrier();

__global__ __launch_bounds__(512, 1) void gemm_qk(const ushort* __restrict__ A,
                                                  const ushort* __restrict__ Bt,
                                                  const float* __restrict__ bias,
                                                  ushort* __restrict__ q,
                                                  ushort* __restrict__ k) {
  __shared__ __align__(16) ushort sA[2][256 * 64];
  __shared__ __align__(16) ushort sB[2][256 * 64];
  const int tid = threadIdx.x, lane = tid & 63, w = tid >> 6;
  const int wm = w >> 2, wn = w & 3;
  const int lr = lane & 15, lg = lane >> 4;

  const int id = blockIdx.x;                 // 256 blocks, bijective
  const int xcd = id & 7, j = id >> 3;       // j in [0,32)
  const int by = xcd * 4 + (j & 3);          // [0,32)
  const int bx = j >> 2;                     // [0,8)
  const int bm = by * 256, bn = bx * 256;

  f32x4 acc[2][4][2][2] = {};
  bf16x8 af[4][2], bf[2][2];

  QK_STAGE(&sA[0][0], A, bm, 0);
  QK_STAGE(&sB[0][0], Bt, bn, 0);
  asm volatile("s_waitcnt vmcnt(0)" ::: "memory");
  __builtin_amdgcn_s_barrier();

  for (int T = 0; T < 16; ++T) {
    const int cur = T & 1;
    const bool pf = (T + 1 < 16);
    QK_LDA(cur, 0); QK_LDB(cur, 0);
    if (pf) QK_STAGE(&sA[cur ^ 1][0], A, bm, (T + 1) * 64);
    QK_SYNC_MMQ(0, 0);
    QK_LDB(cur, 1);
    if (pf) QK_STAGE(&sB[cur ^ 1][0], Bt, bn, (T + 1) * 64);
    QK_SYNC_MMQ(0, 1);
    QK_LDA(cur, 1);
    QK_SYNC_MMQ(1, 1);
    QK_LDB(cur, 0);
    asm volatile("s_waitcnt vmcnt(0)" ::: "memory");
    QK_SYNC_MMQ(1, 0);
  }

  ushort* const dst = (bn < 1024) ? q : k;   // block-uniform
  const int cb = bn & 1023;
  #pragma unroll
  for (int mh = 0; mh < 2; ++mh)
    #pragma unroll
    for (int mi = 0; mi < 4; ++mi)
      #pragma unroll
      for (int nh = 0; nh < 2; ++nh)
        #pragma unroll
        for (int ni = 0; ni < 2; ++ni) {
          const int cq = cb + wn * 64 + nh * 32 + ni * 16 + lr;
          const int h = cq >> 6, d = cq & 63;
          const float bb = bias[bn + wn * 64 + nh * 32 + ni * 16 + lr];
          #pragma unroll
          for (int r = 0; r < 4; ++r) {
            const int row = bm + wm * 128 + mh * 64 + mi * 16 + lg * 4 + r;
            const int b_ = row >> 11, n = row & 2047;
            const int bh = b_ * 16 + h;
            dst[((size_t)bh * 2048 + n) * 64 + d] = f2bf(acc[mh][mi][nh][ni][r] + bb);
          }
        }
}

// ---------------- GEMM core 128x128 (vT/out): counted-vmcnt 2-phase (r10) ----

#define GEMM_STAGE(buf, Ap, Bp, kt)                                            \
  {                                                                            \
    _Pragma("unroll")                                                          \
    for (int c_ = 0; c_ < 4; ++c_) {                                           \
      const int qq_ = c_ * 256 + tid;                                          \
      const int row_ = qq_ >> 3;                                               \
      const int so_ = ((qq_ & 7) ^ (row_ & 7)) * 8;                            \
      gload_lds16(Ap + (size_t)(bm + row_) * 1024 + (kt) + so_,                \
                  (char*)sA + (buf) * 16384 + qq_ * 16);                       \
      gload_lds16(Bp + (size_t)(bn + row_) * 1024 + (kt) + so_,                \
                  (char*)sB + (buf) * 16384 + qq_ * 16);                       \
    }                                                                          \
  }

#define GEMM_COMPUTE(buf)                                                      \
  {                                                                            \
    const char* bA_ = (const char*)sA + (buf) * 16384;                         \
    const char* bB_ = (const char*)sB + (buf) * 16384;                         \
    bf16x8 af[4][2], bfr[4][2];                                                \
    _Pragma("unroll")                                                          \
    for (int mi = 0; mi < 4; ++mi) {                                           \
      const int row_ = wr * 64 + mi * 16 + lr;                                 \
      const char* p_ = bA_ + row_ * 128;                                       \
      const int sw_ = (row_ & 7) << 4;                                         \
      af[mi][0] = *(const bf16x8*)(p_ + ((lg * 16) ^ sw_));                    \
      af[mi][1] = *(const bf16x8*)(p_ + ((64 + lg * 16) ^ sw_));               \
    }                                                                          \
    _Pragma("unroll")                                                          \
    for (int ni = 0; ni < 4; ++ni) {                                           \
      const int row_ = wc * 64 + ni * 16 + lr;                                 \
      const char* p_ = bB_ + row_ * 128;                                       \
      const int sw_ = (row_ & 7) << 4;                                         \
      bfr[ni][0] = *(const bf16x8*)(p_ + ((lg * 16) ^ sw_));                   \
      bfr[ni][1] = *(const bf16x8*)(p_ + ((64 + lg * 16) ^ sw_));              \
    }                                                                          \
    _Pragma("unroll")                                                          \
    for (int kk = 0; kk < 2; ++kk)                                             \
      _Pragma("unroll")                                                        \
      for (int mi = 0; mi < 4; ++mi)                                           \
        _Pragma("unroll")                                                      \
        for (int ni = 0; ni < 4; ++ni)                                         \
          acc[mi][ni] = __builtin_amdgcn_mfma_f32_16x16x32_bf16(               \
              af[mi][kk], bfr[ni][kk], acc[mi][ni], 0, 0, 0);                  \
  }

#define GEMM_PIPELINE(Ap, Bp)                                                  \
  GEMM_STAGE(0, Ap, Bp, 0);                                                    \
  for (int T = 0; T < 16; ++T) {                                               \
    if (T + 1 < 16) {                                                          \
      GEMM_STAGE((T + 1) & 1, Ap, Bp, (T + 1) * 64);                           \
      asm volatile("s_waitcnt vmcnt(8)" ::: "memory");                         \
    } else {                                                                   \
      asm volatile("s_waitcnt vmcnt(0)" ::: "memory");                         \
    }                                                                          \
    __builtin_amdgcn_s_barrier();                                              \
    __builtin_amdgcn_sched_barrier(0);                                         \
    GEMM_COMPUTE(T & 1);                                                       \
    __builtin_amdgcn_s_barrier();                                              \
  }

#define GEMM_PROLOG                                                            \
  __shared__ __align__(16) ushort sA[2][128 * 64];                             \
  __shared__ __align__(16) ushort sB[2][128 * 64];                             \
  const int tid = threadIdx.x;                                                 \
  const int lane = tid & 63;                                                   \
  const int w = tid >> 6;                                                      \
  const int wr = w >> 1, wc = w & 1;                                           \
  const int lr = lane & 15, lg = lane >> 4;                                    \
  f32x4 acc[4][4] = {};

// ---------------- GEMM1b: vT (r10) ----------------

__global__ __launch_bounds__(256) void gemm_vT(const ushort* __restrict__ A,
                                               const ushort* __restrict__ Bt,
                                               const float* __restrict__ bias,
                                               ushort* __restrict__ vT) {
  GEMM_PROLOG;
  const int id = blockIdx.x;                // 512 blocks
  const int xcd = id & 7, j = id >> 3;      // j in [0,64)
  const int bnb = xcd * 8 + (j & 7);        // token-block [0,64)
  const int bmb = j >> 3;                   // v-col block [0,8)
  const int bm = bmb * 128;
  const int bn = bnb * 128;

  GEMM_PIPELINE(A, Bt);

  const int b_ = bn >> 11, n0 = bn & 2047;
  #pragma unroll
  for (int mi = 0; mi < 4; ++mi)
    #pragma unroll
    for (int ni = 0; ni < 4; ++ni) {
      const int ncol = wc * 64 + ni * 16 + lr;
      #pragma unroll
      for (int r = 0; r < 4; ++r) {
        const int m = wr * 64 + mi * 16 + lg * 4 + r;
        const int vc = bm + m;
        const int h = vc >> 6, d = vc & 63;
        const int bh = b_ * 16 + h;
        const float bb = bias[vc];
        vT[((size_t)bh * 64 + d) * 2048 + n0 + ncol] = f2bf(acc[mi][ni][r] + bb);
      }
    }
}

// ---------------- GEMM2: out (r10) ----------------

__global__ __launch_bounds__(256) void gemm_out(const ushort* __restrict__ A,
                                                const ushort* __restrict__ Bt,
                                                const float* __restrict__ bias,
                                                float* __restrict__ out) {
  GEMM_PROLOG;
  const int id = blockIdx.x;                // 512 blocks
  const int xcd = id & 7, j = id >> 3;      // j in [0,64)
  const int by = xcd * 8 + (j & 7);         // A-row block [0,64)
  const int bx = j >> 3;                    // col block [0,8)
  const int bm = by * 128;
  const int bn = bx * 128;

  GEMM_PIPELINE(A, Bt);

  #pragma unroll
  for (int mi = 0; mi < 4; ++mi)
    #pragma unroll
    for (int ni = 0; ni < 4; ++ni) {
      const int col = bn + wc * 64 + ni * 16 + lr;
      const float bb = bias[col];
      #pragma unroll
      for (int r = 0; r < 4; ++r) {
        const int row = bm + wr * 64 + mi * 16 + lg * 4 + r;
        out[(size_t)row * 1024 + col] = acc[mi][ni][r] + bb;
      }
    }
}

// ---------------- flash attention (r10-proven, exact) ----------------

__global__ __launch_bounds__(512, 2) void attn_fwd(const ushort* __restrict__ q,
                                                   const ushort* __restrict__ k,
                                                   const ushort* __restrict__ vT,
                                                   ushort* __restrict__ o) {
  __shared__ __align__(16) ushort sK[2][64 * 64];
  __shared__ __align__(16) ushort sV[2][64 * 64];

  const int tid = threadIdx.x, lane = tid & 63, w = tid >> 6;
  const int id = blockIdx.x;
  const int xcd = id & 7, j = id >> 3;
  const int bh = xcd * 8 + (j & 7);
  const int qx = j >> 3;
  const int qrow0 = qx * 256 + w * 32;

  const ushort* Qb = q + (size_t)bh * 2048 * 64;
  const ushort* Kb = k + (size_t)bh * 2048 * 64;
  const ushort* Vb = vT + (size_t)bh * 64 * 2048;
  const int lq = lane & 31, hi = lane >> 5;

  const int srow = lane >> 3;
  const int ssw = ((lane & 7) ^ srow) * 8;
  const int krow = w * 8 + srow;

  gload_lds16(Kb + (size_t)krow * 64 + ssw, &sK[0][w * 512]);
  gload_lds16(Vb + (size_t)krow * 2048 + 0 + ssw, &sV[0][w * 512]);

  const float qs = 0.125f * 1.44269504f;  // 1/sqrt(64) * log2(e)
  bf16x8 qf[4];
  #pragma unroll
  for (int dk = 0; dk < 4; ++dk) {
    bf16x8 t = *(const bf16x8*)(Qb + (size_t)(qrow0 + lq) * 64 + dk * 16 + hi * 8);
    #pragma unroll
    for (int jj = 0; jj < 8; ++jj)
      t[jj] = (short)f2bf(bf2f((ushort)t[jj]) * qs);
    qf[dk] = t;
  }

  float m_run = -1e30f, l_run = 0.f;
  f32x16 oacc[2] = {};

  for (int t = 0; t < 32; ++t) {
    const int cur = t & 1;
    if (t + 1 < 32) {
      const int kv2 = (t + 1) << 6;
      gload_lds16(Kb + (size_t)(kv2 + krow) * 64 + ssw, &sK[cur ^ 1][w * 512]);
      gload_lds16(Vb + (size_t)krow * 2048 + kv2 + ssw, &sV[cur ^ 1][w * 512]);
      asm volatile("s_waitcnt vmcnt(2)" ::: "memory");
    } else {
      asm volatile("s_waitcnt vmcnt(0)" ::: "memory");
    }
    __builtin_amdgcn_s_barrier();
    __builtin_amdgcn_sched_barrier(0);

    const char* kb_ = (const char*)&sK[cur][0];
    const char* vb_ = (const char*)&sV[cur][0];

    f32x16 S[2] = {};
    __builtin_amdgcn_s_setprio(1);
    #pragma unroll
    for (int kvt = 0; kvt < 2; ++kvt) {
      const int row = kvt * 32 + lq;
      const int rsw = (row & 7) << 4;
      #pragma unroll
      for (int dk = 0; dk < 4; ++dk) {
        bf16x8 kf = *(const bf16x8*)(kb_ + row * 128 + ((dk * 32 + hi * 16) ^ rsw));
        S[kvt] = __builtin_amdgcn_mfma_f32_32x32x16_bf16(kf, qf[dk], S[kvt], 0, 0, 0);
      }
    }
    __builtin_amdgcn_s_setprio(0);

    float mx = S[0][0];
    #pragma unroll
    for (int kvt = 0; kvt < 2; ++kvt)
      #pragma unroll
      for (int r = 0; r < 16; ++r) mx = fmaxf(mx, S[kvt][r]);
    const float rm = fmaxf(mx, __shfl_xor(mx, 32, 64));

    if (!__all(rm <= m_run + 8.f)) {
      const float mnew = fmaxf(m_run, rm);
      const float corr = __builtin_amdgcn_exp2f(m_run - mnew);
      m_run = mnew;
      l_run *= corr;
      float cq[16];
      #pragma unroll
      for (int r = 0; r < 16; ++r)
        cq[r] = __shfl(corr, (r & 3) + 8 * (r >> 2) + 4 * hi, 64);
      #pragma unroll
      for (int dt = 0; dt < 2; ++dt)
        #pragma unroll
        for (int r = 0; r < 16; ++r) oacc[dt][r] *= cq[r];
    }

    float psum = 0.f;
    unsigned pk_[2][8];
    #pragma unroll
    for (int kvt = 0; kvt < 2; ++kvt) {
      float e[16];
      #pragma unroll
      for (int r = 0; r < 16; ++r) {
        e[r] = __builtin_amdgcn_exp2f(S[kvt][r] - m_run);
        psum += e[r];
      }
      #pragma unroll
      for (int g = 0; g < 4; ++g) {
        pk_[kvt][g * 2 + 0] = cvt_pk_bf16(e[4 * g + 0], e[4 * g + 1]);
        pk_[kvt][g * 2 + 1] = cvt_pk_bf16(e[4 * g + 2], e[4 * g + 3]);
      }
    }
    psum += __shfl_xor(psum, 32, 64);
    l_run += psum;

    __builtin_amdgcn_s_setprio(1);
    #pragma unroll
    for (int kvt = 0; kvt < 2; ++kvt)
      #pragma unroll
      for (int cc = 0; cc < 2; ++cc) {
        unsigned x0 = pk_[kvt][4 * cc + 0], x1 = pk_[kvt][4 * cc + 1];
        unsigned y0 = pk_[kvt][4 * cc + 2], y1 = pk_[kvt][4 * cc + 3];
        permlane32_swap(x0, y0);
        permlane32_swap(x1, y1);
        union { unsigned u[4]; bf16x8 v; } Am;
        Am.u[0] = x0; Am.u[1] = x1; Am.u[2] = y0; Am.u[3] = y1;
        const int cg = kvt * 2 + cc;
        #pragma unroll
        for (int dt = 0; dt < 2; ++dt) {
          const int row = dt * 32 + lq;
          bf16x8 vf = *(const bf16x8*)(vb_ + row * 128 + ((cg * 32 + hi * 16) ^ ((row & 7) << 4)));
          oacc[dt] = __builtin_amdgcn_mfma_f32_32x32x16_bf16(Am.v, vf, oacc[dt], 0, 0, 0);
        }
      }
    __builtin_amdgcn_s_setprio(0);
    __builtin_amdgcn_s_barrier();
  }

  const int b_ = bh >> 4, h = bh & 15;
  float lf[16];
  #pragma unroll
  for (int r = 0; r < 16; ++r)
    lf[r] = __builtin_amdgcn_rcpf(__shfl(l_run, (r & 3) + 8 * (r >> 2) + 4 * hi, 64));
  #pragma unroll
  for (int dt = 0; dt < 2; ++dt)
    #pragma unroll
    for (int r = 0; r < 16; ++r) {
      const int n = qrow0 + (r & 3) + 8 * (r >> 2) + 4 * hi;
      o[(((size_t)b_ * 2048 + n) * 16 + h) * 64 + dt * 32 + lq] = f2bf(oacc[dt][r] * lf[r]);
    }
}

// ---------------- launch ----------------

extern "C" void kernel_launch(void* const* d_in, const int* in_sizes, int n_in,
                              void* d_out, int out_size, void* d_ws, size_t ws_size,
                              hipStream_t stream) {
  const float* x = (const float*)d_in[0];
  const float* w_qkv = (const float*)d_in[1];
  const float* b_qkv = (const float*)d_in[2];
  const float* w_out = (const float*)d_in[3];
  const float* b_out = (const float*)d_in[4];
  float* out = (float*)d_out;
  char* ws = (char*)d_ws;

  ushort* xb    = (ushort*)(ws);                 // 16 MiB
  ushort* wqkvT = (ushort*)(ws + 16777216);      // 6 MiB
  ushort* woutT = (ushort*)(ws + 23068672);      // 2 MiB
  ushort* qb    = (ushort*)(ws + 25165824);      // 16 MiB
  ushort* kb    = (ushort*)(ws + 41943040);      // 16 MiB
  ushort* vTb   = (ushort*)(ws + 58720256);      // 16 MiB
  ushort* attnb = (ushort*)(ws + 75497472);      // 16 MiB

  prep<<<6144, 256, 0, stream>>>(x, w_qkv, w_out, xb, wqkvT, woutT);
  gemm_qk<<<256, 512, 0, stream>>>(xb, wqkvT, b_qkv, qb, kb);
  gemm_vT<<<512, 256, 0, stream>>>(wqkvT + 2048 * 1024, xb, b_qkv + 2048, vTb);
  attn_fwd<<<512, 512, 0, stream>>>(qb, kb, vTb, attnb);
  gemm_out<<<512, 256, 0, stream>>>(attnb, woutT, b_out, out);
}